// Round 5
// baseline (79.265 us; speedup 1.0000x reference)
//
#include <hip/hip_runtime.h>
#include <math.h>
#include <stdint.h>

#define B_    8
#define N_    2048
#define FIN   256
#define FO    128
#define ALPHA 0.2f
#define NCHUNK 64
#define CHUNK  32   // N_/NCHUNK

// ---------------- workspace layout (float elements) ----------------
static const size_t OFF_WH    = 0;                                   // B*N*FO
static const size_t OFF_S1    = OFF_WH    + (size_t)B_*N_*FO;
static const size_t OFF_S2    = OFF_S1    + (size_t)B_*N_;
static const size_t OFF_SSORT = OFF_S2    + (size_t)B_*N_;
static const size_t OFF_SORD  = OFF_SSORT + (size_t)B_*N_;
static const size_t OFF_E2P   = OFF_SORD  + (size_t)B_*N_;
static const size_t OFF_E2N   = OFF_E2P   + (size_t)B_*N_;
static const size_t OFF_DPN   = OFF_E2N   + (size_t)B_*N_;           // float2 * B*N
static const size_t OFF_KCUT  = OFF_DPN   + (size_t)2*B_*N_;
static const size_t OFF_OFFS  = OFF_KCUT  + (size_t)B_*N_;           // float2 * B*NCHUNK*FO
static const size_t OFF_SNTOT = OFF_OFFS  + (size_t)2*B_*NCHUNK*FO;
static const size_t OFF_CT    = OFF_SNTOT + (size_t)B_*FO;           // float2 * B*NCHUNK*FO
static const size_t OFF_SUB   = OFF_CT    + (size_t)2*B_*NCHUNK*FO;  // float2 * B*NCHUNK*3*FO

// ---------------- K1: Wh = h @ W (+ fused s1,s2) ----------------
// grid 512 blocks (BM=32 rows), 256 threads, 4m x 4n per thread, K-step 32.
// 2 blocks/CU -> 2 waves/SIMD for stall overlap.
__global__ __launch_bounds__(256) void k1_gemm(const float* __restrict__ h,
                                               const float* __restrict__ W,
                                               const float* __restrict__ a,
                                               float* __restrict__ Wh,
                                               float* __restrict__ s1g,
                                               float* __restrict__ s2g) {
    __shared__ __align__(16) float hS[32][36];     // [k][m] transposed, pad 36
    __shared__ __align__(16) float wS[32][128];    // [k][n]
    __shared__ float red[2][32][33];

    const int tid = threadIdx.x;
    const int tn  = tid & 31;    // cols 4*tn .. +3
    const int tm  = tid >> 5;    // rows 4*tm .. +3
    const int row0 = blockIdx.x * 32;

    const int h_r  = tid >> 3;          // 0..31
    const int h_c0 = (tid & 7) * 4;     // 0,4,..,28

    float acc[4][4];
#pragma unroll
    for (int m = 0; m < 4; ++m)
#pragma unroll
        for (int c = 0; c < 4; ++c) acc[m][c] = 0.f;

    float4 ha, wreg[4];
    // prefetch kt=0
    ha = *(const float4*)&h[(size_t)(row0 + h_r) * FIN + h_c0];
#pragma unroll
    for (int p = 0; p < 4; ++p) {
        int idx = p * 256 + tid, kW = idx >> 5, n4 = (idx & 31) * 4;
        wreg[p] = *(const float4*)&W[(size_t)kW * FO + n4];
    }

    for (int kt = 0; kt < FIN; kt += 32) {
        // registers -> LDS (h transposed)
        hS[h_c0 + 0][h_r] = ha.x; hS[h_c0 + 1][h_r] = ha.y;
        hS[h_c0 + 2][h_r] = ha.z; hS[h_c0 + 3][h_r] = ha.w;
#pragma unroll
        for (int p = 0; p < 4; ++p) {
            int idx = p * 256 + tid, kW = idx >> 5, n4 = (idx & 31) * 4;
            *(float4*)&wS[kW][n4] = wreg[p];
        }
        __syncthreads();

        // issue next tile's global loads
        if (kt + 32 < FIN) {
            ha = *(const float4*)&h[(size_t)(row0 + h_r) * FIN + kt + 32 + h_c0];
#pragma unroll
            for (int p = 0; p < 4; ++p) {
                int idx = p * 256 + tid, kW = idx >> 5, n4 = (idx & 31) * 4;
                wreg[p] = *(const float4*)&W[(size_t)(kt + 32 + kW) * FO + n4];
            }
        }

#pragma unroll 8
        for (int kk = 0; kk < 32; ++kk) {
            float4 hv = *(float4*)&hS[kk][4 * tm];
            float4 wv = *(float4*)&wS[kk][4 * tn];
            float hm[4] = {hv.x, hv.y, hv.z, hv.w};
            float wn4[4] = {wv.x, wv.y, wv.z, wv.w};
#pragma unroll
            for (int m = 0; m < 4; ++m)
#pragma unroll
                for (int c = 0; c < 4; ++c)
                    acc[m][c] += hm[m] * wn4[c];
        }
        __syncthreads();
    }

    // write Wh (b128 stores; 32 tn cover a 512B row)
#pragma unroll
    for (int m = 0; m < 4; ++m) {
        float4 o = make_float4(acc[m][0], acc[m][1], acc[m][2], acc[m][3]);
        *(float4*)&Wh[(size_t)(row0 + 4 * tm + m) * FO + 4 * tn] = o;
    }

    // fused s1/s2
    float a1v[4], a2v[4];
#pragma unroll
    for (int c = 0; c < 4; ++c) {
        a1v[c] = a[4 * tn + c];
        a2v[c] = a[FO + 4 * tn + c];
    }
#pragma unroll
    for (int m = 0; m < 4; ++m) {
        float p1 = 0.f, p2 = 0.f;
#pragma unroll
        for (int c = 0; c < 4; ++c) {
            p1 += acc[m][c] * a1v[c];
            p2 += acc[m][c] * a2v[c];
        }
        red[0][4 * tm + m][tn] = p1;
        red[1][4 * tm + m][tn] = p2;
    }
    __syncthreads();
    if (tid < 64) {
        int arr = tid >> 5, li = tid & 31;
        float s = 0.f;
#pragma unroll
        for (int g = 0; g < 32; ++g) s += red[arr][li][g];
        (arr ? s2g : s1g)[row0 + li] = s;
    }
}

// ---------------- K2a: brute-force rank + scatter + exps ----------------
// grid = B_*32 blocks, 512 threads; block ranks 64 elements, 8 threads/element.
__global__ __launch_bounds__(512) void k2a_rank(const float* __restrict__ s2g,
                                                float* __restrict__ ssort,
                                                int* __restrict__ sord,
                                                float* __restrict__ e2p,
                                                float* __restrict__ e2n) {
    __shared__ uint64_t keys[N_];   // 16 KB
    __shared__ int part[512];
    const int b = blockIdx.x >> 5, c = blockIdx.x & 31;
    const int tid = threadIdx.x;

    for (int t = tid; t < N_; t += 512) {
        unsigned u = __float_as_uint(s2g[b * N_ + t]);
        u = (u & 0x80000000u) ? ~u : (u | 0x80000000u);   // order-preserving map
        keys[t] = ((uint64_t)u << 16) | (unsigned)t;      // unique keys -> no ties
    }
    __syncthreads();

    const int le = tid & 63;
    const int e  = c * 64 + le;
    const int q  = tid >> 6;         // 0..7
    const uint64_t myk = keys[e];
    const uint64_t* kp = keys + q * 256;
    int cnt = 0;
#pragma unroll 8
    for (int kk = 0; kk < 256; ++kk) cnt += (int)(kp[kk] > myk);
    part[tid] = cnt;
    __syncthreads();

    if (tid < 64) {
        int rank = 0;
#pragma unroll
        for (int g = 0; g < 8; ++g) rank += part[tid + 64 * g];
        int ee = c * 64 + tid;
        float v = s2g[b * N_ + ee];
        ssort[b * N_ + rank] = v;
        sord[b * N_ + rank]  = ee;
        e2p[b * N_ + rank] = expf(v);
        e2n[b * N_ + rank] = expf(ALPHA * v);
    }
}

// ---------------- KX: heterogeneous — chunk sums/SUB (blocks 0..511) ∪ scalar scan+cutoffs (512..519) ----------------
__global__ __launch_bounds__(512) void kx_scan(const float* __restrict__ Wh,
                                               const int* __restrict__ sord,
                                               const float* __restrict__ e2p,
                                               const float* __restrict__ e2n,
                                               const float* __restrict__ ssort,
                                               const float* __restrict__ s1g,
                                               float2* __restrict__ SUB,
                                               float2* __restrict__ CT,
                                               float2* __restrict__ DPN,
                                               int* __restrict__ kcut) {
    __shared__ float2 qt[4][FO];     // k3 part
    __shared__ float sv[N_];         // scan part
    __shared__ float2 wsum[8];       // scan part wave totals
    const int tid = threadIdx.x;

    if (blockIdx.x < 512) {
        // ----- chunk part: one 32-chunk; q = tid>>7 owns 8 positions -----
        const int b = blockIdx.x >> 6, ch = blockIdx.x & 63;
        const int f = tid & 127, q = tid >> 7;
        const size_t base = (size_t)b * N_;
        const int ks = ch * CHUNK + q * 8;

        int ords[8]; float wp[8], wn[8], xv[8];
#pragma unroll
        for (int j = 0; j < 8; ++j) ords[j] = sord[base + ks + j];
#pragma unroll
        for (int j = 0; j < 8; ++j) { wp[j] = e2p[base + ks + j]; wn[j] = e2n[base + ks + j]; }
#pragma unroll
        for (int j = 0; j < 8; ++j) xv[j] = Wh[(base + ords[j]) * FO + f];

        float ap = 0.f, an = 0.f;
#pragma unroll
        for (int j = 0; j < 8; ++j) {
            ap += wp[j] * xv[j];
            an += wn[j] * xv[j];
        }
        qt[q][f] = make_float2(ap, an);
        __syncthreads();

        float2 t0 = qt[0][f], t1 = qt[1][f], t2 = qt[2][f];
        float op = 0.f, on = 0.f;
        if (q > 0) { op += t0.x; on += t0.y; }
        if (q > 1) { op += t1.x; on += t1.y; }
        if (q > 2) { op += t2.x; on += t2.y; }
        float2 incl = make_float2(ap + op, an + on);   // inclusive through quarter q
        if (q < 3)
            SUB[(((size_t)b * NCHUNK + ch) * 3 + q) * FO + f] = incl;
        else
            CT[((size_t)b * NCHUNK + ch) * FO + f] = incl;
    } else {
        // ----- scan part: one batch; 512 threads x 4 positions -----
        const int b = blockIdx.x - 512;
        const size_t base = (size_t)b * N_;

        float v[4], pv[4], nv[4], lp[4], ln[4];
        *(float4*)&v[0]  = *(const float4*)&ssort[base + tid * 4];
        *(float4*)&pv[0] = *(const float4*)&e2p[base + tid * 4];
        *(float4*)&nv[0] = *(const float4*)&e2n[base + tid * 4];
        float ap = 0.f, an = 0.f;
#pragma unroll
        for (int j = 0; j < 4; ++j) {
            sv[tid * 4 + j] = v[j];
            ap += pv[j]; lp[j] = ap;
            an += nv[j]; ln[j] = an;
        }

        // wave inclusive scan of per-thread totals
        float ip = ap, in2 = an;
        const int lane = tid & 63;
#pragma unroll
        for (int off = 1; off < 64; off <<= 1) {
            float tpv = __shfl_up(ip, off);
            float tnv = __shfl_up(in2, off);
            if (lane >= off) { ip += tpv; in2 += tnv; }
        }
        if (lane == 63) wsum[tid >> 6] = make_float2(ip, in2);
        __syncthreads();

        float basP = ip - ap, basN = in2 - an;   // exclusive within wave
        const int w = tid >> 6;
#pragma unroll
        for (int w2 = 0; w2 < 7; ++w2) {
            if (w2 < w) { basP += wsum[w2].x; basN += wsum[w2].y; }
        }
#pragma unroll
        for (int j = 0; j < 4; ++j)
            DPN[base + tid * 4 + j] = make_float2(lp[j] + basP, ln[j] + basN);

        // per-row cutoffs: 4 interleaved 11-step binary searches (ILP)
        float tgt[4];
        int lo[4], hi[4];
#pragma unroll
        for (int r = 0; r < 4; ++r) {
            tgt[r] = -s1g[base + tid + 512 * r];
            lo[r] = 0; hi[r] = N_;
        }
#pragma unroll
        for (int step = 0; step < 11; ++step) {
#pragma unroll
            for (int r = 0; r < 4; ++r) {
                int mid = (lo[r] + hi[r]) >> 1;
                bool live = lo[r] < hi[r];
                float pv2 = sv[mid & (N_ - 1)];
                bool cc = live && (pv2 >= tgt[r]);
                lo[r] = cc ? mid + 1 : lo[r];
                hi[r] = (live && !cc) ? mid : hi[r];
            }
        }
#pragma unroll
        for (int r = 0; r < 4; ++r) kcut[base + tid + 512 * r] = lo[r];
    }
}

// ---------------- K3b: per-batch chunk-offset scan in LDS ----------------
// 8 blocks, 256 threads
__global__ __launch_bounds__(256) void k3b_offs(const float2* __restrict__ CT,
                                                float2* __restrict__ OFFS,
                                                float* __restrict__ SNtot) {
    __shared__ float2 ct[NCHUNK][FO];            // 64 KB
    __shared__ float2 halfTot[2][FO];
    const int b = blockIdx.x, tid = threadIdx.x;

    for (int idx = tid; idx < NCHUNK * FO; idx += 256) {
        int c = idx >> 7, f = idx & 127;
        ct[c][f] = CT[((size_t)b * NCHUNK + c) * FO + f];
    }
    __syncthreads();

    const int f = tid & 127, hh = tid >> 7;
    float rp = 0.f, rn = 0.f;
    for (int c = hh * 32; c < hh * 32 + 32; ++c) {
        float2 t = ct[c][f];
        ct[c][f] = make_float2(rp, rn);          // exclusive, local to half
        rp += t.x; rn += t.y;
    }
    halfTot[hh][f] = make_float2(rp, rn);
    __syncthreads();

    float addP = hh ? halfTot[0][f].x : 0.f;
    float addN = hh ? halfTot[0][f].y : 0.f;
    for (int c = hh * 32; c < hh * 32 + 32; ++c) {
        float2 t = ct[c][f];
        OFFS[((size_t)b * NCHUNK + c) * FO + f] = make_float2(t.x + addP, t.y + addN);
    }
    if (tid < FO) SNtot[b * FO + tid] = halfTot[0][tid].y + halfTot[1][tid].y;
}

// ---------------- K4: combine + gather tail + elu ----------------
// grid = B_*N_/2 blocks, 256 threads (2 rows x 128 f)
__global__ __launch_bounds__(256) void k4_final(const float* __restrict__ s1g,
                                                const int* __restrict__ kcut,
                                                const float2* __restrict__ DPN,
                                                const float2* __restrict__ OFFS,
                                                const float2* __restrict__ SUB,
                                                const float* __restrict__ SNtot,
                                                const float* __restrict__ Wh,
                                                const int* __restrict__ sord,
                                                const float* __restrict__ e2p,
                                                const float* __restrict__ e2n,
                                                float* __restrict__ out) {
    const int rowg = blockIdx.x * 2 + (threadIdx.x >> 7);
    const int f = threadIdx.x & 127;
    const int b = rowg >> 11;
    const size_t base = (size_t)b * N_;

    const float s1v = s1g[rowg];
    const int k = kcut[rowg];

    const float ep1 = expf(s1v), en1 = expf(ALPHA * s1v);
    float dp = 0.f, dn = 0.f, sp = 0.f, sn = 0.f;
    if (k > 0) {
        const int km1 = k - 1;
        float2 d = DPN[base + km1];
        dp = d.x; dn = d.y;
        const int c32 = km1 >> 5;
        const int g = (km1 >> 3) & 3;
        float2 o = OFFS[((size_t)b * NCHUNK + c32) * FO + f];
        sp = o.x; sn = o.y;
        if (g > 0) {
            float2 su = SUB[(((size_t)b * NCHUNK + c32) * 3 + (g - 1)) * FO + f];
            sp += su.x; sn += su.y;
        }
        const int j0 = c32 * 32 + g * 8;
        for (int j = j0; j <= km1; ++j) {      // <=8 iterations, wave-uniform
            int ord = sord[base + j];
            float wp = e2p[base + j];
            float wn = e2n[base + j];
            float x = Wh[(base + ord) * FO + f];
            sp += wp * x;
            sn += wn * x;
        }
    }
    const float dnt = DPN[base + N_ - 1].y;
    const float snt = SNtot[b * FO + f];

    const float den = ep1 * dp + en1 * (dnt - dn);
    const float num = ep1 * sp + en1 * (snt - sn);
    const float o = num / den;
    out[(size_t)rowg * FO + f] = (o > 0.f) ? o : (expf(o) - 1.f);
}

// ---------------- launch ----------------
extern "C" void kernel_launch(void* const* d_in, const int* in_sizes, int n_in,
                              void* d_out, int out_size, void* d_ws, size_t ws_size,
                              hipStream_t stream) {
    const float* h = (const float*)d_in[0];
    const float* W = (const float*)d_in[1];
    const float* a = (const float*)d_in[2];
    float* out = (float*)d_out;
    float* ws = (float*)d_ws;

    float*  Wh    = ws + OFF_WH;
    float*  s1    = ws + OFF_S1;
    float*  s2    = ws + OFF_S2;
    float*  ssort = ws + OFF_SSORT;
    int*    sord  = (int*)(ws + OFF_SORD);
    float*  e2p   = ws + OFF_E2P;
    float*  e2n   = ws + OFF_E2N;
    float2* DPN   = (float2*)(ws + OFF_DPN);
    int*    kcut  = (int*)(ws + OFF_KCUT);
    float2* OFFS  = (float2*)(ws + OFF_OFFS);
    float*  SNtot = ws + OFF_SNTOT;
    float2* CT    = (float2*)(ws + OFF_CT);
    float2* SUB   = (float2*)(ws + OFF_SUB);

    k1_gemm<<<dim3(B_ * N_ / 32), dim3(256), 0, stream>>>(h, W, a, Wh, s1, s2);
    k2a_rank<<<dim3(B_ * 32), dim3(512), 0, stream>>>(s2, ssort, sord, e2p, e2n);
    kx_scan<<<dim3(520), dim3(512), 0, stream>>>(Wh, sord, e2p, e2n, ssort, s1,
                                                 SUB, CT, DPN, kcut);
    k3b_offs<<<dim3(B_), dim3(256), 0, stream>>>(CT, OFFS, SNtot);
    k4_final<<<dim3(B_ * N_ / 2), dim3(256), 0, stream>>>(s1, kcut, DPN, OFFS, SUB,
                                                          SNtot, Wh, sord, e2p, e2n, out);
}